// Round 4
// baseline (209.751 us; speedup 1.0000x reference)
//
#include <hip/hip_runtime.h>
#include <stdint.h>

#define N_NODES 100000
#define N_FEAT 128
#define N_EDGES 3200000

// ---------- bf16 helpers ----------
static __device__ __forceinline__ unsigned int f2bf_u(float f) {
    unsigned int u = __float_as_uint(f);
    u += 0x7FFFu + ((u >> 16) & 1u);   // RNE
    return u >> 16;
}

typedef __bf16 bf16x8 __attribute__((ext_vector_type(8)));
typedef float f32x4 __attribute__((ext_vector_type(4)));

// ---------- Kernel 1 (prep): CSR row_ptr + filters -> bf16 fragment-linear ----------
// blocks [0,12500):      CSR row_ptr scatter from sorted edge_dst
// blocks [12500,12564):  filters -> bf16 in MFMA B-fragment-linear order:
//   flat short index i holds F[k][n] with n = (i>>11)*16 + ((i>>3)&15),
//   k = ((i>>9)&3)*32 + ((i>>7)&3)*8 + (i&7)
__global__ __launch_bounds__(256) void k_prep(
        const float* __restrict__ f, unsigned short* __restrict__ fB,
        const int* __restrict__ dst, int* __restrict__ row_ptr) {
    int b = blockIdx.x;
    if (b < 12500) {
        int e = b * 256 + threadIdx.x;
        if (e >= N_EDGES) return;
        int dcur = dst[e];
        if (e == 0) {
            for (int d = 0; d <= dcur; ++d) row_ptr[d] = 0;
        } else {
            int dprev = dst[e - 1];
            for (int d = dprev + 1; d <= dcur; ++d) row_ptr[d] = e;
        }
        if (e == N_EDGES - 1) {
            for (int d = dcur + 1; d <= N_NODES; ++d) row_ptr[d] = N_EDGES;
        }
    } else {
        int i = (b - 12500) * 256 + threadIdx.x;   // flat fragment-linear index
        if (i >= N_FEAT * N_FEAT) return;
        int n = ((i >> 11) << 4) | ((i >> 3) & 15);
        int k = (((i >> 9) & 3) << 5) | (((i >> 7) & 3) << 3) | (i & 7);
        fB[i] = (unsigned short)f2bf_u(f[k * 128 + n]);
    }
}

// ---------- Kernel 2: XF = x @ F (MFMA), fused biased-uint8 row quantization ----------
// Block 256 (4 waves), 64 rows/block. B in LDS fragment-linear (32KB, 5 blocks/CU).
// Packed xi8 layout: byte b of uint c of a row = feature (32*b + c).
__global__ __launch_bounds__(256) void k_xf(
        const float* __restrict__ x,
        const unsigned short* __restrict__ fB,
        unsigned int* __restrict__ xi8,          // [N][32] uints (4 biased-u8 each)
        float* __restrict__ xscale) {            // [N]
    __shared__ unsigned short Bbuf[16384];       // 32768 B exactly
    int t = threadIdx.x;
    for (int i = 0; i < 8; ++i)
        ((uint4*)Bbuf)[t + i * 256] = ((const uint4*)fB)[t + i * 256];
    __syncthreads();

    int wave = t >> 6, lane = t & 63, m15 = lane & 15, q = lane >> 4;
    int row = blockIdx.x * 64 + wave * 16 + m15;
    int rowc = min(row, N_NODES - 1);            // clamp loads; stores guarded

    f32x4 acc[8];
#pragma unroll
    for (int j = 0; j < 8; ++j) acc[j] = f32x4{0.f, 0.f, 0.f, 0.f};

#pragma unroll
    for (int kkidx = 0; kkidx < 4; ++kkidx) {
        const float* ap = x + (size_t)rowc * 128 + kkidx * 32 + q * 8;
        float4 v0 = *(const float4*)ap;
        float4 v1 = *(const float4*)(ap + 4);
        union { bf16x8 v; unsigned short s[8]; } au;
        au.s[0] = (unsigned short)f2bf_u(v0.x);
        au.s[1] = (unsigned short)f2bf_u(v0.y);
        au.s[2] = (unsigned short)f2bf_u(v0.z);
        au.s[3] = (unsigned short)f2bf_u(v0.w);
        au.s[4] = (unsigned short)f2bf_u(v1.x);
        au.s[5] = (unsigned short)f2bf_u(v1.y);
        au.s[6] = (unsigned short)f2bf_u(v1.z);
        au.s[7] = (unsigned short)f2bf_u(v1.w);
#pragma unroll
        for (int j = 0; j < 8; ++j) {
            bf16x8 bfrag = *(const bf16x8*)(Bbuf + (((j * 4 + kkidx) * 64 + lane) * 8));
            acc[j] = __builtin_amdgcn_mfma_f32_16x16x32_bf16(au.v, bfrag, acc[j], 0, 0, 0);
        }
    }

    int rowbase = blockIdx.x * 64 + wave * 16 + q * 4;   // D: row=q*4+r, col=j*16+m15
#pragma unroll
    for (int r = 0; r < 4; ++r) {
        float mx = 0.f;
#pragma unroll
        for (int j = 0; j < 8; ++j) mx = fmaxf(mx, fabsf(acc[j][r]));
        for (int d = 1; d < 16; d <<= 1) mx = fmaxf(mx, __shfl_xor(mx, d));
        float inv = 127.f / fmaxf(mx, 1e-20f);
        unsigned int u0 = 0, u1 = 0;
#pragma unroll
        for (int bb = 0; bb < 4; ++bb) {
            unsigned int q0 = (unsigned int)(int)(rintf(acc[2 * bb][r] * inv) + 128.f);
            unsigned int q1 = (unsigned int)(int)(rintf(acc[2 * bb + 1][r] * inv) + 128.f);
            u0 |= (q0 & 0xFFu) << (8 * bb);
            u1 |= (q1 & 0xFFu) << (8 * bb);
        }
        int gr = rowbase + r;
        if (gr < N_NODES) {
            xi8[(size_t)gr * 32 + m15] = u0;       // uint c=m15      (feats 32b+c)
            xi8[(size_t)gr * 32 + 16 + m15] = u1;  // uint c=16+m15
            if (m15 == 0) xscale[gr] = mx * (1.f / 127.f);
        }
    }
}

// ---------- Kernel 3: out[d] = sum_e w_e * xscale[s] * (q_u - 128) -> fp32 direct ----------
// Round-1 shape (16-edge groups, 8 dword gathers each, lane covers uint f=lane&31
// of edge parity half=lane>>5) + explicit 2-stage software pipeline: while the
// FMA block of group j runs, group j+1's 8 gathers are in flight (16 total, 4KB/wave).
// -128 bias via aw (sum of folded weights) accumulated at staging -- exact.
__global__ __launch_bounds__(256) void k_aggregate(
        const unsigned int* __restrict__ xi8,    // [N][32] uints (4 biased-u8 each)
        const float* __restrict__ xscale,        // [N]
        const int* __restrict__ src,
        const float* __restrict__ w,
        const int* __restrict__ row_ptr,
        float* __restrict__ out) {               // [N][128] fp32 (final output)
    __shared__ uint2 smeta[4][64];
    int wave = threadIdx.x >> 6, lane = threadIdx.x & 63;
    int node = blockIdx.x * 4 + wave;
    if (node >= N_NODES) return;
    int half = lane >> 5, f = lane & 31;
    unsigned int fo = (unsigned int)(f * 4);         // byte offset within 128B row
    int start = row_ptr[node], end = row_ptr[node + 1];
    uint2* sm = smeta[wave];
    const char* xb = (const char*)xi8;

    float a0 = 0.f, a1 = 0.f, a2 = 0.f, a3 = 0.f, aw = 0.f;

#define LOADG(J, VV, WW) do {                                              \
        _Pragma("unroll")                                                  \
        for (int u = 0; u < 8; ++u) {                                      \
            uint2 mm = sm[(J) * 16 + u * 2 + half];                        \
            WW[u] = __uint_as_float(mm.y);                                 \
            VV[u] = *(const unsigned int*)(xb + (mm.x + fo));              \
        } } while (0)
#define FMAG(VV, WW) do {                                                  \
        _Pragma("unroll")                                                  \
        for (int u = 0; u < 8; ++u) {                                      \
            unsigned int v = VV[u]; float wu = WW[u];                      \
            a0 = fmaf(wu, (float)( v        & 0xFFu), a0);                 \
            a1 = fmaf(wu, (float)((v >>  8) & 0xFFu), a1);                 \
            a2 = fmaf(wu, (float)((v >> 16) & 0xFFu), a2);                 \
            a3 = fmaf(wu, (float)( v >> 24         ), a3);                 \
        } } while (0)

    for (int e0 = start; e0 < end; e0 += 64) {
        int e = e0 + lane;
        uint2 m = make_uint2(0u, 0u);                // pad: row 0, w'=0
        if (e < end) {
            int sv = src[e];
            m.x = (unsigned int)sv << 7;             // row byte offset
            m.y = __float_as_uint(w[e] * xscale[sv]);// fold row scale
        }
        sm[lane] = m;                                // wave-private; no barrier
        aw += __uint_as_float(m.y);                  // bias sum (staging phase)
        int nj = (min(64, end - e0) + 15) >> 4;      // 16-edge groups (>=1)
        unsigned int vA[8], vB[8]; float wA[8], wB[8];
        LOADG(0, vA, wA);
        int j = 0;
        for (; j + 2 <= nj; j += 2) {
            LOADG(j + 1, vB, wB);                    // 16 gathers in flight
            FMAG(vA, wA);
            if (j + 2 < nj) LOADG(j + 2, vA, wA);
            FMAG(vB, wB);
        }
        if (j < nj) FMAG(vA, wA);
    }
#undef LOADG
#undef FMAG

    // combine edge-parity halves; aw over the whole wave
    a0 += __shfl_xor(a0, 32);
    a1 += __shfl_xor(a1, 32);
    a2 += __shfl_xor(a2, 32);
    a3 += __shfl_xor(a3, 32);
    aw += __shfl_xor(aw, 1);
    aw += __shfl_xor(aw, 2);
    aw += __shfl_xor(aw, 4);
    aw += __shfl_xor(aw, 8);
    aw += __shfl_xor(aw, 16);
    aw += __shfl_xor(aw, 32);

    if (half == 0) {
        // uint f bytes 0..3 -> feats f, 32+f, 64+f, 96+f  (undo +128 bias via aw)
        float* o = out + (size_t)node * 128 + f;
        o[ 0] = fmaf(-128.f, aw, a0);
        o[32] = fmaf(-128.f, aw, a1);
        o[64] = fmaf(-128.f, aw, a2);
        o[96] = fmaf(-128.f, aw, a3);
    }
}

extern "C" void kernel_launch(void* const* d_in, const int* in_sizes, int n_in,
                              void* d_out, int out_size, void* d_ws, size_t ws_size,
                              hipStream_t stream) {
    const float* x        = (const float*)d_in[0];
    const float* filters  = (const float*)d_in[1];
    const int*   edge_src = (const int*)d_in[2];
    const int*   edge_dst = (const int*)d_in[3];
    const float* edge_w   = (const float*)d_in[4];
    float* out = (float*)d_out;

    char* ws = (char*)d_ws;
    unsigned int*   xi8 = (unsigned int*)  (ws);                          // 12.8 MB
    float*          xsc = (float*)         (ws + 13ll * 1024 * 1024);     // 400 KB
    unsigned short* fB  = (unsigned short*)(ws + 14ll * 1024 * 1024);     // 32 KB
    int*            rp  = (int*)           (ws + 15ll * 1024 * 1024);     // 400 KB

    hipLaunchKernelGGL(k_prep, dim3(12564), dim3(256), 0, stream,
                       filters, fB, edge_dst, rp);
    hipLaunchKernelGGL(k_xf, dim3(1563), dim3(256), 0, stream,
                       x, fB, xi8, xsc);
    hipLaunchKernelGGL(k_aggregate, dim3(25000), dim3(256), 0, stream,
                       xi8, xsc, edge_src, edge_w, rp, out);
}